// Round 1
// baseline (1396.927 us; speedup 1.0000x reference)
//
#include <hip/hip_runtime.h>
#include <hip/hip_bf16.h>
#include <stdint.h>

// GCN1: x3 = adj@(x2@W3)+b3; x2 = adj@(x1@W2)+b2; x1 = drop(relu(adj@(x@W1)+b1))
// All heavy GEMMs in bf16 MFMA (2% rel tolerance), exact JAX threefry dropout.

#define MROWS 10000
#define KPAD  10016   // 10000 padded to multiple of 32

typedef __attribute__((ext_vector_type(8))) short short8;
typedef __attribute__((ext_vector_type(4))) float floatx4;

__device__ __forceinline__ unsigned short f2bf(float f) {
  union { float f; unsigned u; } v; v.f = f;
  unsigned u = v.u;
  u += 0x7fffu + ((u >> 16) & 1u);   // round-to-nearest-even
  return (unsigned short)(u >> 16);
}

// ---- exact JAX threefry2x32-20, key(42) = (0, 42), iota split in halves ----
__device__ __forceinline__ bool dropout_keep(unsigned i) {
  const unsigned halfn = 2560000u;           // (10000*512)/2
  const unsigned j = (i < halfn) ? i : (i - halfn);
  unsigned x0 = j, x1 = j + halfn;
  const unsigned k0 = 0u, k1 = 42u, k2 = 0u ^ 42u ^ 0x1BD11BDAu;
  x0 += k0; x1 += k1;
#define TFR(r) { x0 += x1; x1 = (x1 << (r)) | (x1 >> (32 - (r))); x1 ^= x0; }
  TFR(13) TFR(15) TFR(26) TFR(6)   x0 += k1; x1 += k2 + 1u;
  TFR(17) TFR(29) TFR(16) TFR(24)  x0 += k2; x1 += k0 + 2u;
  TFR(13) TFR(15) TFR(26) TFR(6)   x0 += k0; x1 += k1 + 3u;
  TFR(17) TFR(29) TFR(16) TFR(24)  x0 += k1; x1 += k2 + 4u;
  TFR(13) TFR(15) TFR(26) TFR(6)   x0 += k2; x1 += k0 + 5u;
#undef TFR
  const unsigned bits = (i < halfn) ? x0 : x1;
  // uniform u = bitcast((bits>>9)|0x3f800000)-1 < 0.5  <=>  bits < 2^31 (exact)
  return bits < 0x80000000u;
}

// ---- cast kernels ----
__global__ void cast_adj_kernel(const float* __restrict__ in, unsigned short* __restrict__ out) {
  const int q = blockIdx.x * blockDim.x + threadIdx.x;  // quad of 4 cols
  const int row = blockIdx.y;
  if (q >= 2504) return;                                 // 10016/4
  const int col = q * 4;
  ushort4 o;
  if (col < 10000) {
    const float4 v = *(const float4*)(in + (size_t)row * 10000 + col);
    o.x = f2bf(v.x); o.y = f2bf(v.y); o.z = f2bf(v.z); o.w = f2bf(v.w);
  } else {
    o.x = 0; o.y = 0; o.z = 0; o.w = 0;                  // K-pad zeros
  }
  *(ushort4*)(out + (size_t)row * KPAD + col) = o;
}

__global__ void cast_vec_kernel(const float* __restrict__ in, unsigned short* __restrict__ out, int n4) {
  const int id = blockIdx.x * blockDim.x + threadIdx.x;
  if (id >= n4) return;
  const float4 v = ((const float4*)in)[id];
  ushort4 o; o.x = f2bf(v.x); o.y = f2bf(v.y); o.z = f2bf(v.z); o.w = f2bf(v.w);
  ((ushort4*)out)[id] = o;
}

// W (K x N) f32 -> W^T (N x K) bf16
__global__ void castT_kernel(const float* __restrict__ in, unsigned short* __restrict__ out, int K, int N) {
  const int id = blockIdx.x * blockDim.x + threadIdx.x;
  if (id >= K * N) return;
  const int n = id / K, k = id % K;
  out[(size_t)n * K + k] = f2bf(in[(size_t)k * N + n]);
}

// zero pad cols 10000..10016 of an (rows x KPAD) buffer
__global__ void zero_pad_kernel(unsigned short* __restrict__ p, int rows) {
  const int id = blockIdx.x * blockDim.x + threadIdx.x;
  if (id >= rows * 16) return;
  const int r = id >> 4, c = id & 15;
  p[(size_t)r * KPAD + 10000 + c] = 0;
}

// ---- bf16 MFMA GEMM: C = A(MxK) @ BT'(KxN) [+bias, +relu/dropout] ----
// OUT_KIND: 0 = bf16 transposed store (C^T, ldc = row stride of C^T)
//           1 = bf16 row-major, 2 = f32 row-major
// EPI: 0 none, 1 +bias, 2 +bias,relu,dropout(x2)
template<int OUT_KIND, int EPI>
__global__ __launch_bounds__(256, 2) void gemm_mfma(
    const unsigned short* __restrict__ A, int lda,
    const unsigned short* __restrict__ BT, int ldb,
    void* __restrict__ Cv, int ldc,
    const float* __restrict__ bias,
    int M, int N, int K)
{
  __shared__ unsigned short As[128 * 32];
  __shared__ unsigned short Bs[128 * 32];

  const int tid  = threadIdx.x;
  const int lane = tid & 63;
  const int wave = tid >> 6;
  const int m0 = blockIdx.y * 128;
  const int n0 = blockIdx.x * 128;
  const int wm = (wave & 1) * 64;
  const int wn = (wave >> 1) * 64;

  floatx4 acc[4][4];
#pragma unroll
  for (int i = 0; i < 4; ++i)
#pragma unroll
    for (int j = 0; j < 4; ++j) acc[i][j] = (floatx4){0.f, 0.f, 0.f, 0.f};

  // staging: tile is 128 rows x 32 k (bf16) = 512 x 16B chunks; thread does chunks tid, tid+256
  const int c1 = tid, c2 = tid + 256;
  int ar1 = m0 + (c1 >> 2); if (ar1 > M - 1) ar1 = M - 1;   // row clamp (tail tiles)
  int ar2 = m0 + (c2 >> 2); if (ar2 > M - 1) ar2 = M - 1;
  const int br1 = n0 + (c1 >> 2);                           // N is a multiple of 128
  const int br2 = n0 + (c2 >> 2);
  const unsigned short* aG1 = A  + (size_t)ar1 * lda + (c1 & 3) * 8;
  const unsigned short* aG2 = A  + (size_t)ar2 * lda + (c2 & 3) * 8;
  const unsigned short* bG1 = BT + (size_t)br1 * ldb + (c1 & 3) * 8;
  const unsigned short* bG2 = BT + (size_t)br2 * ldb + (c2 & 3) * 8;
  unsigned short* lA1 = As + c1 * 8;
  unsigned short* lA2 = As + c2 * 8;
  unsigned short* lB1 = Bs + c1 * 8;
  unsigned short* lB2 = Bs + c2 * 8;

  const int fr = lane & 15;
  const int fq = (lane >> 4) * 8;

#define GLL16(g, l) __builtin_amdgcn_global_load_lds( \
    (const __attribute__((address_space(1))) void*)(g), \
    (__attribute__((address_space(3))) void*)(l), 16, 0, 0)

  for (int k0 = 0; k0 < K; k0 += 32) {
    GLL16(aG1 + k0, lA1);
    GLL16(aG2 + k0, lA2);
    GLL16(bG1 + k0, lB1);
    GLL16(bG2 + k0, lB2);
    __syncthreads();   // drains vmcnt -> LDS ready
    short8 af[4], bfv[4];
#pragma unroll
    for (int mi = 0; mi < 4; ++mi)
      af[mi] = *(const short8*)(As + (wm + mi * 16 + fr) * 32 + fq);
#pragma unroll
    for (int ni = 0; ni < 4; ++ni)
      bfv[ni] = *(const short8*)(Bs + (wn + ni * 16 + fr) * 32 + fq);
#pragma unroll
    for (int mi = 0; mi < 4; ++mi)
#pragma unroll
      for (int ni = 0; ni < 4; ++ni)
        acc[mi][ni] = __builtin_amdgcn_mfma_f32_16x16x32_bf16(af[mi], bfv[ni], acc[mi][ni], 0, 0, 0);
    __syncthreads();   // protect LDS before next stage
  }
#undef GLL16

  if (OUT_KIND == 0) {
    // C^T store: C^T[n][m], 4 consecutive m per lane -> ushort4
    unsigned short* Ct = (unsigned short*)Cv;
#pragma unroll
    for (int mi = 0; mi < 4; ++mi) {
      const int mbase = m0 + wm + mi * 16 + (lane >> 4) * 4;  // 4-aligned; M%4==0
      if (mbase < M) {
#pragma unroll
        for (int ni = 0; ni < 4; ++ni) {
          const int n = n0 + wn + ni * 16 + fr;
          ushort4 o;
          o.x = f2bf(acc[mi][ni][0]);
          o.y = f2bf(acc[mi][ni][1]);
          o.z = f2bf(acc[mi][ni][2]);
          o.w = f2bf(acc[mi][ni][3]);
          *(ushort4*)(Ct + (size_t)n * ldc + mbase) = o;
        }
      }
    }
  } else {
#pragma unroll
    for (int ni = 0; ni < 4; ++ni) {
      const int col = n0 + wn + ni * 16 + fr;
      const float bv = (EPI >= 1) ? bias[col] : 0.0f;
#pragma unroll
      for (int mi = 0; mi < 4; ++mi) {
        const int rbase = m0 + wm + mi * 16 + (lane >> 4) * 4;
#pragma unroll
        for (int r = 0; r < 4; ++r) {
          const int row = rbase + r;
          if (row < M) {
            float v = acc[mi][ni][r] + bv;
            if (EPI == 2) {
              v = v > 0.f ? v : 0.f;
              const unsigned idx = (unsigned)row * (unsigned)N + (unsigned)col;
              v = dropout_keep(idx) ? v * 2.0f : 0.0f;
            }
            if (OUT_KIND == 2)
              ((float*)Cv)[(size_t)row * ldc + col] = v;
            else
              ((unsigned short*)Cv)[(size_t)row * ldc + col] = f2bf(v);
          }
        }
      }
    }
  }
}

extern "C" void kernel_launch(void* const* d_in, const int* in_sizes, int n_in,
                              void* d_out, int out_size, void* d_ws, size_t ws_size,
                              hipStream_t stream) {
  const float* x   = (const float*)d_in[0];
  const float* adj = (const float*)d_in[1];
  const float* W1  = (const float*)d_in[2];
  const float* b1  = (const float*)d_in[3];
  const float* W2  = (const float*)d_in[4];
  const float* b2  = (const float*)d_in[5];
  const float* W3  = (const float*)d_in[6];
  const float* b3  = (const float*)d_in[7];
  float* out = (float*)d_out;

  char* ws = (char*)d_ws;
  unsigned short* adjb = (unsigned short*)(ws);                  // 10000 x 10016 bf16
  unsigned short* xb   = (unsigned short*)(ws + 200320000ull);   // 10000 x 1024
  unsigned short* w1t  = (unsigned short*)(ws + 220800000ull);   // 512 x 1024 (W1^T)
  unsigned short* w2t  = (unsigned short*)(ws + 221848576ull);   // 256 x 512
  unsigned short* w3t  = (unsigned short*)(ws + 222110720ull);   // 128 x 256
  unsigned short* h1t  = (unsigned short*)(ws + 222176256ull);   // 512 x 10016 (H1^T)
  unsigned short* x1   = (unsigned short*)(ws + 232432640ull);   // 10000 x 512
  unsigned short* h2t  = (unsigned short*)(ws + 242672640ull);   // 256 x 10016
  unsigned short* x2   = (unsigned short*)(ws + 247800832ull);   // 10000 x 256
  unsigned short* h3t  = (unsigned short*)(ws + 252920832ull);   // 128 x 10016
  // total ~255.5 MB of d_ws

  cast_adj_kernel<<<dim3(10, 10000), 256, 0, stream>>>(adj, adjb);
  cast_vec_kernel<<<10000, 256, 0, stream>>>(x, xb, 2560000);
  castT_kernel<<<2048, 256, 0, stream>>>(W1, w1t, 1024, 512);
  castT_kernel<<<512, 256, 0, stream>>>(W2, w2t, 512, 256);
  castT_kernel<<<128, 256, 0, stream>>>(W3, w3t, 256, 128);
  zero_pad_kernel<<<32, 256, 0, stream>>>(h1t, 512);
  zero_pad_kernel<<<16, 256, 0, stream>>>(h2t, 256);
  zero_pad_kernel<<<8, 256, 0, stream>>>(h3t, 128);

  // H1^T = (x @ W1)^T
  gemm_mfma<0, 0><<<dim3(4, 79), 256, 0, stream>>>(xb, 1024, w1t, 1024, h1t, KPAD, nullptr, MROWS, 512, 1024);
  // x1 = dropout(relu(adj @ H1 + b1))
  gemm_mfma<1, 2><<<dim3(4, 79), 256, 0, stream>>>(adjb, KPAD, h1t, KPAD, x1, 512, b1, MROWS, 512, KPAD);
  // H2^T = (x1 @ W2)^T
  gemm_mfma<0, 0><<<dim3(2, 79), 256, 0, stream>>>(x1, 512, w2t, 512, h2t, KPAD, nullptr, MROWS, 256, 512);
  // x2 = adj @ H2 + b2
  gemm_mfma<1, 1><<<dim3(2, 79), 256, 0, stream>>>(adjb, KPAD, h2t, KPAD, x2, 256, b2, MROWS, 256, KPAD);
  // H3^T = (x2 @ W3)^T
  gemm_mfma<0, 0><<<dim3(1, 79), 256, 0, stream>>>(x2, 256, w3t, 256, h3t, KPAD, nullptr, MROWS, 128, 256);
  // out = adj @ H3 + b3  (f32)
  gemm_mfma<2, 1><<<dim3(1, 79), 256, 0, stream>>>(adjb, KPAD, h3t, KPAD, out, 128, b3, MROWS, 128, KPAD);
}

// Round 2
// 1119.156 us; speedup vs baseline: 1.2482x; 1.2482x over previous
//
#include <hip/hip_runtime.h>
#include <hip/hip_bf16.h>
#include <stdint.h>

// GCN1: x3 = adj@(x2@W3)+b3; x2 = adj@(x1@W2)+b2; x1 = drop(relu(adj@(x@W1)+b1))
// bf16 MFMA GEMMs (2% rel tolerance), exact JAX threefry dropout.
// R2: split-K for the three adj GEMMs (they were latency-bound at <1.5 blocks/CU).

#define MROWS 10000
#define KPAD  10016   // 10000 padded to multiple of 32 (313 k-iters)

typedef __attribute__((ext_vector_type(8))) short short8;
typedef __attribute__((ext_vector_type(4))) float floatx4;

__device__ __forceinline__ unsigned short f2bf(float f) {
  union { float f; unsigned u; } v; v.f = f;
  unsigned u = v.u;
  u += 0x7fffu + ((u >> 16) & 1u);   // round-to-nearest-even
  return (unsigned short)(u >> 16);
}

// ---- exact JAX threefry2x32-20, key(42) = (0, 42), iota split in halves ----
__device__ __forceinline__ bool dropout_keep(unsigned i) {
  const unsigned halfn = 2560000u;           // (10000*512)/2
  const unsigned j = (i < halfn) ? i : (i - halfn);
  unsigned x0 = j, x1 = j + halfn;
  const unsigned k0 = 0u, k1 = 42u, k2 = 0u ^ 42u ^ 0x1BD11BDAu;
  x0 += k0; x1 += k1;
#define TFR(r) { x0 += x1; x1 = (x1 << (r)) | (x1 >> (32 - (r))); x1 ^= x0; }
  TFR(13) TFR(15) TFR(26) TFR(6)   x0 += k1; x1 += k2 + 1u;
  TFR(17) TFR(29) TFR(16) TFR(24)  x0 += k2; x1 += k0 + 2u;
  TFR(13) TFR(15) TFR(26) TFR(6)   x0 += k0; x1 += k1 + 3u;
  TFR(17) TFR(29) TFR(16) TFR(24)  x0 += k1; x1 += k2 + 4u;
  TFR(13) TFR(15) TFR(26) TFR(6)   x0 += k2; x1 += k0 + 5u;
#undef TFR
  const unsigned bits = (i < halfn) ? x0 : x1;
  return bits < 0x80000000u;   // uniform(bits) < 0.5, exact transform
}

// ---- cast kernels ----
__global__ void cast_adj_kernel(const float* __restrict__ in, unsigned short* __restrict__ out) {
  const int q = blockIdx.x * blockDim.x + threadIdx.x;  // quad of 4 cols
  const int row = blockIdx.y;
  if (q >= 2504) return;                                 // 10016/4
  const int col = q * 4;
  ushort4 o;
  if (col < 10000) {
    const float4 v = *(const float4*)(in + (size_t)row * 10000 + col);
    o.x = f2bf(v.x); o.y = f2bf(v.y); o.z = f2bf(v.z); o.w = f2bf(v.w);
  } else {
    o.x = 0; o.y = 0; o.z = 0; o.w = 0;                  // K-pad zeros
  }
  *(ushort4*)(out + (size_t)row * KPAD + col) = o;
}

__global__ void cast_vec_kernel(const float* __restrict__ in, unsigned short* __restrict__ out, int n4) {
  const int id = blockIdx.x * blockDim.x + threadIdx.x;
  if (id >= n4) return;
  const float4 v = ((const float4*)in)[id];
  ushort4 o; o.x = f2bf(v.x); o.y = f2bf(v.y); o.z = f2bf(v.z); o.w = f2bf(v.w);
  ((ushort4*)out)[id] = o;
}

// W (K x N) f32 -> W^T (N x K) bf16
__global__ void castT_kernel(const float* __restrict__ in, unsigned short* __restrict__ out, int K, int N) {
  const int id = blockIdx.x * blockDim.x + threadIdx.x;
  if (id >= K * N) return;
  const int n = id / K, k = id % K;
  out[(size_t)n * K + k] = f2bf(in[(size_t)k * N + n]);
}

// zero pad cols 10000..10016 of an (rows x KPAD) buffer
__global__ void zero_pad_kernel(unsigned short* __restrict__ p, int rows) {
  const int id = blockIdx.x * blockDim.x + threadIdx.x;
  if (id >= rows * 16) return;
  const int r = id >> 4, c = id & 15;
  p[(size_t)r * KPAD + 10000 + c] = 0;
}

// ---- bf16 MFMA GEMM: C = A(MxK) @ BT'(KxN) ----
// OUT_KIND: 0 = bf16 transposed store (C^T, ldc = row stride of C^T)
//           1 = bf16 row-major, 2 = f32 row-major,
//           3 = f32 partial (split-K): P[z*M*N + row*N + col] = acc  (no bias)
// EPI: 0 none, 1 +bias, 2 +bias,relu,dropout(x2)   (ignored for OUT_KIND 0/3)
template<int OUT_KIND, int EPI>
__global__ __launch_bounds__(256, 2) void gemm_mfma(
    const unsigned short* __restrict__ A, int lda,
    const unsigned short* __restrict__ BT, int ldb,
    void* __restrict__ Cv, int ldc,
    const float* __restrict__ bias,
    int M, int N, int K,
    int chunk)      // k-iters*32 per split (OUT_KIND==3); else pass K
{
  __shared__ unsigned short As[128 * 32];
  __shared__ unsigned short Bs[128 * 32];

  const int tid  = threadIdx.x;
  const int lane = tid & 63;
  const int wave = tid >> 6;
  const int m0 = blockIdx.y * 128;
  const int n0 = blockIdx.x * 128;
  const int wm = (wave & 1) * 64;
  const int wn = (wave >> 1) * 64;

  int kstart = 0, kend = K;
  if (OUT_KIND == 3) {
    kstart = blockIdx.z * chunk;
    kend   = kstart + chunk; if (kend > K) kend = K;
  }

  floatx4 acc[4][4];
#pragma unroll
  for (int i = 0; i < 4; ++i)
#pragma unroll
    for (int j = 0; j < 4; ++j) acc[i][j] = (floatx4){0.f, 0.f, 0.f, 0.f};

  // staging: tile is 128 rows x 32 k (bf16) = 512 x 16B chunks; thread does chunks tid, tid+256
  const int c1 = tid, c2 = tid + 256;
  int ar1 = m0 + (c1 >> 2); if (ar1 > M - 1) ar1 = M - 1;   // row clamp (tail tiles)
  int ar2 = m0 + (c2 >> 2); if (ar2 > M - 1) ar2 = M - 1;
  const int br1 = n0 + (c1 >> 2);                           // N is a multiple of 128
  const int br2 = n0 + (c2 >> 2);
  const unsigned short* aG1 = A  + (size_t)ar1 * lda + (c1 & 3) * 8;
  const unsigned short* aG2 = A  + (size_t)ar2 * lda + (c2 & 3) * 8;
  const unsigned short* bG1 = BT + (size_t)br1 * ldb + (c1 & 3) * 8;
  const unsigned short* bG2 = BT + (size_t)br2 * ldb + (c2 & 3) * 8;
  unsigned short* lA1 = As + c1 * 8;
  unsigned short* lA2 = As + c2 * 8;
  unsigned short* lB1 = Bs + c1 * 8;
  unsigned short* lB2 = Bs + c2 * 8;

  const int fr = lane & 15;
  const int fq = (lane >> 4) * 8;

#define GLL16(g, l) __builtin_amdgcn_global_load_lds( \
    (const __attribute__((address_space(1))) void*)(g), \
    (__attribute__((address_space(3))) void*)(l), 16, 0, 0)

  for (int k0 = kstart; k0 < kend; k0 += 32) {
    GLL16(aG1 + k0, lA1);
    GLL16(aG2 + k0, lA2);
    GLL16(bG1 + k0, lB1);
    GLL16(bG2 + k0, lB2);
    __syncthreads();   // drains vmcnt -> LDS ready
    short8 af[4], bfv[4];
#pragma unroll
    for (int mi = 0; mi < 4; ++mi)
      af[mi] = *(const short8*)(As + (wm + mi * 16 + fr) * 32 + fq);
#pragma unroll
    for (int ni = 0; ni < 4; ++ni)
      bfv[ni] = *(const short8*)(Bs + (wn + ni * 16 + fr) * 32 + fq);
#pragma unroll
    for (int mi = 0; mi < 4; ++mi)
#pragma unroll
      for (int ni = 0; ni < 4; ++ni)
        acc[mi][ni] = __builtin_amdgcn_mfma_f32_16x16x32_bf16(af[mi], bfv[ni], acc[mi][ni], 0, 0, 0);
    __syncthreads();   // protect LDS before next stage
  }
#undef GLL16

  if (OUT_KIND == 0) {
    // C^T store: C^T[n][m], 4 consecutive m per lane -> ushort4
    unsigned short* Ct = (unsigned short*)Cv;
#pragma unroll
    for (int mi = 0; mi < 4; ++mi) {
      const int mbase = m0 + wm + mi * 16 + (lane >> 4) * 4;  // 4-aligned; M%4==0
      if (mbase < M) {
#pragma unroll
        for (int ni = 0; ni < 4; ++ni) {
          const int n = n0 + wn + ni * 16 + fr;
          ushort4 o;
          o.x = f2bf(acc[mi][ni][0]);
          o.y = f2bf(acc[mi][ni][1]);
          o.z = f2bf(acc[mi][ni][2]);
          o.w = f2bf(acc[mi][ni][3]);
          *(ushort4*)(Ct + (size_t)n * ldc + mbase) = o;
        }
      }
    }
  } else if (OUT_KIND == 3) {
    float* P = (float*)Cv + (size_t)blockIdx.z * (size_t)M * (size_t)N;
#pragma unroll
    for (int ni = 0; ni < 4; ++ni) {
      const int col = n0 + wn + ni * 16 + fr;
#pragma unroll
      for (int mi = 0; mi < 4; ++mi) {
        const int rbase = m0 + wm + mi * 16 + (lane >> 4) * 4;
#pragma unroll
        for (int r = 0; r < 4; ++r) {
          const int row = rbase + r;
          if (row < M) P[(size_t)row * N + col] = acc[mi][ni][r];
        }
      }
    }
  } else {
#pragma unroll
    for (int ni = 0; ni < 4; ++ni) {
      const int col = n0 + wn + ni * 16 + fr;
      const float bv = (EPI >= 1) ? bias[col] : 0.0f;
#pragma unroll
      for (int mi = 0; mi < 4; ++mi) {
        const int rbase = m0 + wm + mi * 16 + (lane >> 4) * 4;
#pragma unroll
        for (int r = 0; r < 4; ++r) {
          const int row = rbase + r;
          if (row < M) {
            float v = acc[mi][ni][r] + bv;
            if (EPI == 2) {
              v = v > 0.f ? v : 0.f;
              const unsigned idx = (unsigned)row * (unsigned)N + (unsigned)col;
              v = dropout_keep(idx) ? v * 2.0f : 0.0f;
            }
            if (OUT_KIND == 2)
              ((float*)Cv)[(size_t)row * ldc + col] = v;
            else
              ((unsigned short*)Cv)[(size_t)row * ldc + col] = f2bf(v);
          }
        }
      }
    }
  }
}

// ---- split-K reduce + epilogue ----
// EPI: 2 = bias+relu+dropout -> bf16; 1 = bias -> bf16; 3 = bias -> f32
template<int EPI>
__global__ void reduce_epi_kernel(const float* __restrict__ P, void* __restrict__ outv,
                                  const float* __restrict__ bias,
                                  int S, int total4, unsigned nmask, size_t MN) {
  const int t = blockIdx.x * blockDim.x + threadIdx.x;
  if (t >= total4) return;
  const size_t off = (size_t)t * 4;
  float4 a = *(const float4*)(P + off);
  for (int s = 1; s < S; ++s) {
    const float4 b = *(const float4*)(P + (size_t)s * MN + off);
    a.x += b.x; a.y += b.y; a.z += b.z; a.w += b.w;
  }
  const unsigned col = (unsigned)off & nmask;   // N power of 2; off%4==0
  a.x += bias[col]; a.y += bias[col + 1]; a.z += bias[col + 2]; a.w += bias[col + 3];
  if (EPI == 2) {
    float* e = &a.x;
#pragma unroll
    for (int j = 0; j < 4; ++j) {
      float v = e[j] > 0.f ? e[j] : 0.f;
      e[j] = dropout_keep((unsigned)off + j) ? v * 2.0f : 0.0f;
    }
  }
  if (EPI == 3) {
    *(float4*)((float*)outv + off) = a;
  } else {
    ushort4 o;
    o.x = f2bf(a.x); o.y = f2bf(a.y); o.z = f2bf(a.z); o.w = f2bf(a.w);
    *(ushort4*)((unsigned short*)outv + off) = o;
  }
}

static inline int pick_split(size_t avail, size_t per_split, int target) {
  int s = 1;
  while (s < target && (size_t)(s * 2) * per_split <= avail) s *= 2;
  return s;
}

extern "C" void kernel_launch(void* const* d_in, const int* in_sizes, int n_in,
                              void* d_out, int out_size, void* d_ws, size_t ws_size,
                              hipStream_t stream) {
  const float* x   = (const float*)d_in[0];
  const float* adj = (const float*)d_in[1];
  const float* W1  = (const float*)d_in[2];
  const float* b1  = (const float*)d_in[3];
  const float* W2  = (const float*)d_in[4];
  const float* b2  = (const float*)d_in[5];
  const float* W3  = (const float*)d_in[6];
  const float* b3  = (const float*)d_in[7];
  float* out = (float*)d_out;

  char* ws = (char*)d_ws;
  unsigned short* adjb = (unsigned short*)(ws);                  // 10000 x 10016 bf16
  unsigned short* xb   = (unsigned short*)(ws + 200320000ull);   // 10000 x 1024
  unsigned short* w1t  = (unsigned short*)(ws + 220800000ull);   // 512 x 1024 (W1^T)
  unsigned short* w2t  = (unsigned short*)(ws + 221848576ull);   // 256 x 512
  unsigned short* w3t  = (unsigned short*)(ws + 222110720ull);   // 128 x 256
  unsigned short* h1t  = (unsigned short*)(ws + 222176256ull);   // 512 x 10016 (H1^T)
  unsigned short* x1   = (unsigned short*)(ws + 232432640ull);   // 10000 x 512
  unsigned short* h2t  = (unsigned short*)(ws + 242672640ull);   // 256 x 10016
  unsigned short* x2   = (unsigned short*)(ws + 247800832ull);   // 10000 x 256
  unsigned short* h3t  = (unsigned short*)(ws + 252920832ull);   // 128 x 10016
  float*          P    = (float*)(ws + 255484928ull);            // split-K partials
  const size_t avail = (ws_size > 255484928ull) ? ws_size - 255484928ull : 0;

  // split factors (target 1264 blocks each); per-split partial sizes in bytes
  const int S1 = pick_split(avail, 20480000ull, 4);   // 10000x512 f32
  const int S2 = pick_split(avail, 10240000ull, 8);   // 10000x256 f32
  const int S3 = pick_split(avail,  5120000ull, 16);  // 10000x128 f32

  cast_adj_kernel<<<dim3(10, 10000), 256, 0, stream>>>(adj, adjb);
  cast_vec_kernel<<<10000, 256, 0, stream>>>(x, xb, 2560000);
  castT_kernel<<<2048, 256, 0, stream>>>(W1, w1t, 1024, 512);
  castT_kernel<<<512, 256, 0, stream>>>(W2, w2t, 512, 256);
  castT_kernel<<<128, 256, 0, stream>>>(W3, w3t, 256, 128);
  zero_pad_kernel<<<32, 256, 0, stream>>>(h1t, 512);
  zero_pad_kernel<<<16, 256, 0, stream>>>(h2t, 256);
  zero_pad_kernel<<<8, 256, 0, stream>>>(h3t, 128);

  // H1^T = (x @ W1)^T
  gemm_mfma<0, 0><<<dim3(4, 79), 256, 0, stream>>>(xb, 1024, w1t, 1024, h1t, KPAD, nullptr, MROWS, 512, 1024, 1024);

  // x1 = dropout(relu(adj @ H1 + b1))
  if (S1 > 1) {
    const int chunk = ((313 + S1 - 1) / S1) * 32;
    gemm_mfma<3, 0><<<dim3(4, 79, S1), 256, 0, stream>>>(adjb, KPAD, h1t, KPAD, P, 512, nullptr, MROWS, 512, KPAD, chunk);
    reduce_epi_kernel<2><<<5000, 256, 0, stream>>>(P, x1, b1, S1, 1280000, 511u, 5120000ull);
  } else {
    gemm_mfma<1, 2><<<dim3(4, 79), 256, 0, stream>>>(adjb, KPAD, h1t, KPAD, x1, 512, b1, MROWS, 512, KPAD, KPAD);
  }

  // H2^T = (x1 @ W2)^T
  gemm_mfma<0, 0><<<dim3(2, 79), 256, 0, stream>>>(x1, 512, w2t, 512, h2t, KPAD, nullptr, MROWS, 256, 512, 512);

  // x2 = adj @ H2 + b2
  if (S2 > 1) {
    const int chunk = ((313 + S2 - 1) / S2) * 32;
    gemm_mfma<3, 0><<<dim3(2, 79, S2), 256, 0, stream>>>(adjb, KPAD, h2t, KPAD, P, 256, nullptr, MROWS, 256, KPAD, chunk);
    reduce_epi_kernel<1><<<2500, 256, 0, stream>>>(P, x2, b2, S2, 640000, 255u, 2560000ull);
  } else {
    gemm_mfma<1, 1><<<dim3(2, 79), 256, 0, stream>>>(adjb, KPAD, h2t, KPAD, x2, 256, b2, MROWS, 256, KPAD, KPAD);
  }

  // H3^T = (x2 @ W3)^T
  gemm_mfma<0, 0><<<dim3(1, 79), 256, 0, stream>>>(x2, 256, w3t, 256, h3t, KPAD, nullptr, MROWS, 128, 256, 256);

  // out = adj @ H3 + b3  (f32)
  if (S3 > 1) {
    const int chunk = ((313 + S3 - 1) / S3) * 32;
    gemm_mfma<3, 0><<<dim3(1, 79, S3), 256, 0, stream>>>(adjb, KPAD, h3t, KPAD, P, 128, nullptr, MROWS, 128, KPAD, chunk);
    reduce_epi_kernel<3><<<1250, 256, 0, stream>>>(P, out, b3, S3, 320000, 127u, 1280000ull);
  } else {
    gemm_mfma<2, 1><<<dim3(1, 79), 256, 0, stream>>>(adjb, KPAD, h3t, KPAD, out, 128, b3, MROWS, 128, KPAD, KPAD);
  }
}